// Round 4
// baseline (2555.379 us; speedup 1.0000x reference)
//
#include <hip/hip_runtime.h>
#include <math.h>

#define PPB 2048
#define NBATCH 8
#define KNN 20

// ---------------------------------------------------------------------------
// Register-tiled fp32 GEMM: Y[i][m] = sum_k X[i*ldx+k]*W[m*ldw+k] (+bias[m])
// Block tile 128(i) x BN(m), thread tile 8 x TN, K-tile 8, 256 threads.
// ---------------------------------------------------------------------------
template <int BN, int TN>
__global__ __launch_bounds__(256) void gemm_kernel(
    const float* __restrict__ X, int ldx,
    const float* __restrict__ W, int ldw,
    const float* __restrict__ bias,
    float* __restrict__ Y, int ldy, int D) {
  __shared__ float Xs[8][132];
  __shared__ float Ws[8][BN + 4];
  int t = threadIdx.x;
  int tx = t & 15, ty = t >> 4;
  int i0 = blockIdx.y * 128, m0 = blockIdx.x * BN;
  float acc[8][TN];
#pragma unroll
  for (int r = 0; r < 8; ++r)
#pragma unroll
    for (int n = 0; n < TN; ++n) acc[r][n] = 0.f;

  for (int k0 = 0; k0 < D; k0 += 8) {
#pragma unroll
    for (int p = 0; p < 4; ++p) {
      int e = t + p * 256, r = e >> 3, c = e & 7, k = k0 + c;
      Xs[c][r] = (k < D) ? X[(size_t)(i0 + r) * ldx + k] : 0.f;
    }
#pragma unroll
    for (int p = 0; p < BN * 8 / 256; ++p) {
      int e = t + p * 256, r = e >> 3, c = e & 7, k = k0 + c;
      Ws[c][r] = (k < D) ? W[(size_t)(m0 + r) * ldw + k] : 0.f;
    }
    __syncthreads();
#pragma unroll
    for (int k = 0; k < 8; ++k) {
      float4 a0 = *(const float4*)&Xs[k][ty * 8];
      float4 a1 = *(const float4*)&Xs[k][ty * 8 + 4];
      float a[8] = {a0.x, a0.y, a0.z, a0.w, a1.x, a1.y, a1.z, a1.w};
      float b[TN];
#pragma unroll
      for (int n4 = 0; n4 < TN / 4; ++n4) {
        float4 bb = *(const float4*)&Ws[k][tx * TN + n4 * 4];
        b[n4 * 4 + 0] = bb.x; b[n4 * 4 + 1] = bb.y;
        b[n4 * 4 + 2] = bb.z; b[n4 * 4 + 3] = bb.w;
      }
#pragma unroll
      for (int r = 0; r < 8; ++r)
#pragma unroll
        for (int n = 0; n < TN; ++n) acc[r][n] += a[r] * b[n];
    }
    __syncthreads();
  }
#pragma unroll
  for (int r = 0; r < 8; ++r) {
    size_t row = (size_t)(i0 + ty * 8 + r) * ldy + m0 + tx * TN;
#pragma unroll
    for (int n4 = 0; n4 < TN / 4; ++n4) {
      float4 o;
      o.x = acc[r][n4 * 4 + 0]; o.y = acc[r][n4 * 4 + 1];
      o.z = acc[r][n4 * 4 + 2]; o.w = acc[r][n4 * 4 + 3];
      if (bias) {
        const float* bp = bias + m0 + tx * TN + n4 * 4;
        o.x += bp[0]; o.y += bp[1]; o.z += bp[2]; o.w += bp[3];
      }
      *(float4*)&Y[row + n4 * 4] = o;
    }
  }
}

// ---------------------------------------------------------------------------
// fc1 GEMM (576 -> 1024) fused with max over the 128-point block tile.
// ---------------------------------------------------------------------------
__global__ __launch_bounds__(256) void fc1max_kernel(
    const float* __restrict__ X, int ldx,
    const float* __restrict__ W, int ldw,
    const float* __restrict__ bias,
    float* __restrict__ partial, int D) {
  __shared__ float Xs[8][132];
  __shared__ float Ws[8][132];
  __shared__ float red[16][128];
  int t = threadIdx.x;
  int tx = t & 15, ty = t >> 4;
  int b = blockIdx.z, pt = blockIdx.y;
  int i0 = b * PPB + pt * 128;
  int m0 = blockIdx.x * 128;
  float acc[8][8];
#pragma unroll
  for (int r = 0; r < 8; ++r)
#pragma unroll
    for (int n = 0; n < 8; ++n) acc[r][n] = 0.f;

  for (int k0 = 0; k0 < D; k0 += 8) {
#pragma unroll
    for (int p = 0; p < 4; ++p) {
      int e = t + p * 256, r = e >> 3, c = e & 7, k = k0 + c;
      Xs[c][r] = (k < D) ? X[(size_t)(i0 + r) * ldx + k] : 0.f;
      Ws[c][r] = (k < D) ? W[(size_t)(m0 + r) * ldw + k] : 0.f;
    }
    __syncthreads();
#pragma unroll
    for (int k = 0; k < 8; ++k) {
      float4 a0 = *(const float4*)&Xs[k][ty * 8];
      float4 a1 = *(const float4*)&Xs[k][ty * 8 + 4];
      float a[8] = {a0.x, a0.y, a0.z, a0.w, a1.x, a1.y, a1.z, a1.w};
      float4 b0 = *(const float4*)&Ws[k][tx * 8];
      float4 b1 = *(const float4*)&Ws[k][tx * 8 + 4];
      float bb[8] = {b0.x, b0.y, b0.z, b0.w, b1.x, b1.y, b1.z, b1.w};
#pragma unroll
      for (int r = 0; r < 8; ++r)
#pragma unroll
        for (int n = 0; n < 8; ++n) acc[r][n] += a[r] * bb[n];
    }
    __syncthreads();
  }
  float tmax[8];
#pragma unroll
  for (int n = 0; n < 8; ++n) {
    float m = acc[0][n];
#pragma unroll
    for (int r = 1; r < 8; ++r) m = fmaxf(m, acc[r][n]);
    tmax[n] = m + bias[m0 + tx * 8 + n];
  }
#pragma unroll
  for (int n = 0; n < 8; ++n) red[ty][tx * 8 + n] = tmax[n];
  __syncthreads();
  for (int off = 8; off > 0; off >>= 1) {
    if (ty < off) {
#pragma unroll
      for (int n = 0; n < 8; ++n)
        red[ty][tx * 8 + n] = fmaxf(red[ty][tx * 8 + n], red[ty + off][tx * 8 + n]);
    }
    __syncthreads();
  }
  if (ty == 0) {
#pragma unroll
    for (int n = 0; n < 8; ++n)
      partial[((size_t)b * 16 + pt) * 1024 + m0 + tx * 8 + n] = red[0][tx * 8 + n];
  }
}

__global__ __launch_bounds__(256) void gmax_kernel(
    const float* __restrict__ partial, float* __restrict__ g) {
  int b = blockIdx.y;
  int m = blockIdx.x * 256 + threadIdx.x;
  float mx = -INFINITY;
  for (int pt = 0; pt < 16; ++pt)
    mx = fmaxf(mx, partial[((size_t)b * 16 + pt) * 1024 + m]);
  g[b * 1024 + m] = mx;
}

// ---------------------------------------------------------------------------
__global__ __launch_bounds__(192) void h0_kernel(
    const float* __restrict__ pos, const float* __restrict__ xin,
    const float* __restrict__ catbuf, float* __restrict__ h0) {
  int i = blockIdx.x;
  int d = threadIdx.x;
  if (d < 3)        h0[(size_t)i * 134 + d] = pos[i * 3 + d];
  else if (d < 6)   h0[(size_t)i * 134 + d] = xin[i * 3 + d - 3];
  else if (d < 134) h0[(size_t)i * 134 + d] = catbuf[(size_t)i * 576 + 448 + (d - 6)];
}

__global__ __launch_bounds__(64) void sq_kernel(
    const float* __restrict__ X, int ldx, int D, float* __restrict__ sq) {
  int i = blockIdx.x;
  int t = threadIdx.x;
  float s = 0.f;
  for (int k = t; k < D; k += 64) {
    float v = X[(size_t)i * ldx + k];
    s += v * v;
  }
  for (int off = 32; off > 0; off >>= 1) s += __shfl_down(s, off);
  if (t == 0) sq[i] = s;
}

// ---------------------------------------------------------------------------
// Transpose per batch: XT[b][k][j] = X[b*PPB+j][k]
// ---------------------------------------------------------------------------
__global__ __launch_bounds__(256) void transpose_kernel(
    const float* __restrict__ X, int ldx, int D, float* __restrict__ XT) {
  __shared__ float Ts[64][65];
  int b = blockIdx.z;
  int j0 = blockIdx.x * 64;
  int k0 = blockIdx.y * 64;
  int t = threadIdx.x;
#pragma unroll
  for (int p = 0; p < 16; ++p) {
    int e = t + p * 256, r = e >> 6, c = e & 63;
    Ts[r][c] = (k0 + c < D) ? X[(size_t)(b * PPB + j0 + r) * ldx + k0 + c] : 0.f;
  }
  __syncthreads();
#pragma unroll
  for (int p = 0; p < 16; ++p) {
    int e = t + p * 256, r = e >> 6, c = e & 63;
    if (k0 + r < D)
      XT[((size_t)b * D + k0 + r) * PPB + j0 + c] = Ts[c][r];
  }
}

// ---------------------------------------------------------------------------
// knn4: fused dist + top-K.  8 queries/block, 256 threads (4 waves).
// Thread t owns candidates j = 4t..4t+3 and 1024+4t..1024+4t+3 (float4 loads,
// explicit next-k prefetch).  Selection in TWO passes of 4 rows through a
// 32 KB LDS buffer (dist4), so occupancy is 4 blocks/CU instead of 2.
// Selection indexing (j = lane + 64*m) and tie-breaking identical to knn3.
// Rank on sq[j]-2*dot (row-constant sq[i] dropped; ranking identical).
// grid: (PPB/8, NBATCH)
// ---------------------------------------------------------------------------
template <int D>
__global__ __launch_bounds__(256, 4) void knn4_kernel(
    const float* __restrict__ X, int ldx,
    const float* __restrict__ XT,
    const float* __restrict__ sq,
    int* __restrict__ idx) {
  __shared__ float Qs[D][8];
  __shared__ float dist4[4][PPB];
  int b = blockIdx.y;
  int q0 = blockIdx.x * 8;
  int t = threadIdx.x;
  int lane = t & 63, w = t >> 6;

  for (int e = t; e < 8 * D; e += 256) {
    int q = e / D, k = e - q * D;
    Qs[k][q] = X[(size_t)(b * PPB + q0 + q) * ldx + k];
  }
  __syncthreads();

  // candidate pointers: float4 view, row stride = PPB/4 = 512 float4
  const float4* cp4 = (const float4*)(XT + (size_t)b * D * PPB) + t;
  float acc[8][8];
#pragma unroll
  for (int q = 0; q < 8; ++q)
#pragma unroll
    for (int s = 0; s < 8; ++s) acc[q][s] = 0.f;

  float4 c0 = cp4[0];
  float4 c1 = cp4[256];
  for (int k = 0; k < D - 1; ++k) {
    float4 n0 = cp4[(k + 1) * 512];
    float4 n1 = cp4[(k + 1) * 512 + 256];
    float4 q0v = *(const float4*)&Qs[k][0];
    float4 q1v = *(const float4*)&Qs[k][4];
    float qv[8] = {q0v.x, q0v.y, q0v.z, q0v.w, q1v.x, q1v.y, q1v.z, q1v.w};
    float cv[8] = {c0.x, c0.y, c0.z, c0.w, c1.x, c1.y, c1.z, c1.w};
#pragma unroll
    for (int q = 0; q < 8; ++q)
#pragma unroll
      for (int s = 0; s < 8; ++s) acc[q][s] += qv[q] * cv[s];
    c0 = n0; c1 = n1;
  }
  {
    float4 q0v = *(const float4*)&Qs[D - 1][0];
    float4 q1v = *(const float4*)&Qs[D - 1][4];
    float qv[8] = {q0v.x, q0v.y, q0v.z, q0v.w, q1v.x, q1v.y, q1v.z, q1v.w};
    float cv[8] = {c0.x, c0.y, c0.z, c0.w, c1.x, c1.y, c1.z, c1.w};
#pragma unroll
    for (int q = 0; q < 8; ++q)
#pragma unroll
      for (int s = 0; s < 8; ++s) acc[q][s] += qv[q] * cv[s];
  }

  float4 sq0 = ((const float4*)(sq + (size_t)b * PPB))[t];
  float4 sq1 = ((const float4*)(sq + (size_t)b * PPB))[t + 256];
  float sqj[8] = {sq0.x, sq0.y, sq0.z, sq0.w, sq1.x, sq1.y, sq1.z, sq1.w};

  // two selection passes of 4 query rows each
#pragma unroll
  for (int p = 0; p < 2; ++p) {
    __syncthreads();  // pass 0: after Qs use; pass 1: after selection reads
#pragma unroll
    for (int qq = 0; qq < 4; ++qq) {
      int q = p * 4 + qq;
      float4 d0, d1;
      d0.x = sqj[0] - 2.f * acc[q][0]; d0.y = sqj[1] - 2.f * acc[q][1];
      d0.z = sqj[2] - 2.f * acc[q][2]; d0.w = sqj[3] - 2.f * acc[q][3];
      d1.x = sqj[4] - 2.f * acc[q][4]; d1.y = sqj[5] - 2.f * acc[q][5];
      d1.z = sqj[6] - 2.f * acc[q][6]; d1.w = sqj[7] - 2.f * acc[q][7];
      *(float4*)&dist4[qq][4 * t] = d0;
      *(float4*)&dist4[qq][4 * t + 1024] = d1;
    }
    __syncthreads();
    // wave w selects top-K for query p*4+w
    {
      int q = p * 4 + w;
      float v[32];
#pragma unroll
      for (int m = 0; m < 32; ++m) v[m] = dist4[w][lane + 64 * m];
#pragma unroll
      for (int s = 0; s < KNN; ++s) {
        float bv = 1e38f;
        int bm = 0;
#pragma unroll
        for (int m = 0; m < 32; ++m)
          if (v[m] < bv) { bv = v[m]; bm = m; }
        int bj = lane + 64 * bm;
#pragma unroll
        for (int o = 1; o < 64; o <<= 1) {
          float ov = __shfl_xor(bv, o);
          int oj = __shfl_xor(bj, o);
          if (ov < bv || (ov == bv && oj < bj)) { bv = ov; bj = oj; }
        }
        if (lane == 0)
          idx[(size_t)(b * PPB + q0 + q) * KNN + s] = b * PPB + bj;
        bool mine = (lane == (bj & 63));
        int wm = bj >> 6;
#pragma unroll
        for (int m = 0; m < 32; ++m)
          if (mine && m == wm) v[m] = 1e38f;
      }
    }
  }
}

// ---------------------------------------------------------------------------
// EdgeConv epilogue: Y[i][m] = A[i][m] + b[m] - Pb[i][m] + max_kk Pb[nb][m]
// ---------------------------------------------------------------------------
__global__ __launch_bounds__(256) void edge_out_kernel(
    const float* __restrict__ A, const float* __restrict__ Pb, int M,
    const float* __restrict__ bias, const int* __restrict__ idx,
    float* __restrict__ Y, int ldy) {
  int i = blockIdx.x;
  int t = threadIdx.x;
  __shared__ int nbs[KNN];
  if (t < KNN) nbs[t] = idx[(size_t)i * KNN + t];
  __syncthreads();
  for (int m = t; m < M; m += 256) {
    float mx = -INFINITY;
#pragma unroll
    for (int kk = 0; kk < KNN; ++kk)
      mx = fmaxf(mx, Pb[(size_t)nbs[kk] * M + m]);
    Y[(size_t)i * ldy + m] = A[(size_t)i * M + m] + bias[m] - Pb[(size_t)i * M + m] + mx;
  }
}

// ---------------------------------------------------------------------------
__global__ __launch_bounds__(256) void mlp_kernel(
    const float* __restrict__ X, const float* __restrict__ W,
    const float* __restrict__ bias, float* __restrict__ Y,
    int D, int M, int do_relu) {
  int b = blockIdx.y;
  int m = blockIdx.x * 256 + threadIdx.x;
  if (m >= M) return;
  const float* xr = X + (size_t)b * D;
  const float* wr = W + (size_t)m * D;
  float acc = 0.f;
  for (int k = 0; k < D; ++k) acc += xr[k] * wr[k];
  acc += bias[m];
  if (do_relu) acc = fmaxf(acc, 0.f);
  Y[(size_t)b * M + m] = acc;
}

__global__ __launch_bounds__(64) void final_kernel(
    const float* __restrict__ X, const float* __restrict__ W,
    const float* __restrict__ bias, float* __restrict__ out) {
  int b = blockIdx.x;
  int t = threadIdx.x;
  __shared__ float lg[23];
  if (t < 23) {
    const float* xr = X + (size_t)b * 256;
    const float* wr = W + (size_t)t * 256;
    float acc = bias[t];
    for (int k = 0; k < 256; ++k) acc += xr[k] * wr[k];
    lg[t] = acc;
  }
  __syncthreads();
  if (t == 0) {
    float mx = lg[0];
    for (int c = 1; c < 23; ++c) mx = fmaxf(mx, lg[c]);
    float s = 0.f;
    for (int c = 0; c < 23; ++c) s += expf(lg[c] - mx);
    float lse = mx + logf(s);
    for (int c = 0; c < 23; ++c) out[b * 23 + c] = lg[c] - lse;
  }
}

// ---------------------------------------------------------------------------

extern "C" void kernel_launch(void* const* d_in, const int* in_sizes, int n_in,
                              void* d_out, int out_size, void* d_ws, size_t ws_size,
                              hipStream_t stream) {
  const float* pos      = (const float*)d_in[0];
  const float* xin      = (const float*)d_in[1];
  const float* features = (const float*)d_in[2];
  const float* Wf   = (const float*)d_in[4];
  const float* bf   = (const float*)d_in[5];
  const float* W1   = (const float*)d_in[6];
  const float* b1   = (const float*)d_in[7];
  const float* W2   = (const float*)d_in[8];
  const float* b2   = (const float*)d_in[9];
  const float* W3   = (const float*)d_in[10];
  const float* b3   = (const float*)d_in[11];
  const float* Wfc1 = (const float*)d_in[12];
  const float* bfc1 = (const float*)d_in[13];
  const float* Wfa  = (const float*)d_in[14];
  const float* bfa  = (const float*)d_in[15];
  const float* Wfb  = (const float*)d_in[16];
  const float* bfb  = (const float*)d_in[17];
  const float* Wfc  = (const float*)d_in[18];
  const float* bfc  = (const float*)d_in[19];
  float* out = (float*)d_out;

  const int N = in_sizes[0] / 3;  // 16384

  char* base = (char*)d_ws;
  size_t off = 0;
  auto alloc = [&](size_t bytes) {
    void* p = base + off;
    off += (bytes + 255) & ~(size_t)255;
    return p;
  };
  float* catbuf  = (float*)alloc((size_t)N * 576 * 4);  // [x1|x2|x3|feats]
  float* h0      = (float*)alloc((size_t)N * 134 * 4);
  float* Abuf    = (float*)alloc((size_t)N * 256 * 4);
  float* Pbbuf   = (float*)alloc((size_t)N * 256 * 4);
  float* XTbuf   = (float*)alloc((size_t)N * 134 * 4);
  float* sqbuf   = (float*)alloc((size_t)N * 4);
  int*   idxbuf  = (int*)  alloc((size_t)N * KNN * 4);
  float* partial = (float*)alloc((size_t)NBATCH * 16 * 1024 * 4);
  float* g       = (float*)alloc((size_t)NBATCH * 1024 * 4);
  float* ga      = (float*)alloc((size_t)NBATCH * 512 * 4);
  float* gb      = (float*)alloc((size_t)NBATCH * 256 * 4);
  (void)ws_size;

  // 1. feats = features @ Wf.T + bf  -> catbuf[:,448:576]
  gemm_kernel<128, 8><<<dim3(1, N / 128), 256, 0, stream>>>(
      features, 1344, Wf, 1344, bf, catbuf + 448, 576, 1344);

  // 2. h0 = [pos | x | feats]
  h0_kernel<<<N, 192, 0, stream>>>(pos, xin, catbuf, h0);

  struct Layer {
    const float* Xin; int ldx; int D;
    const float* W; int ldw;
    const float* bias; int M;
    float* Yout;
  };
  Layer L[3] = {
      {h0,          134, 134, W1, 268, b1,  64, catbuf + 0},
      {catbuf + 0,  576,  64, W2, 128, b2, 128, catbuf + 64},
      {catbuf + 64, 576, 128, W3, 256, b3, 256, catbuf + 192},
  };

  for (int l = 0; l < 3; ++l) {
    sq_kernel<<<N, 64, 0, stream>>>(L[l].Xin, L[l].ldx, L[l].D, sqbuf);
    transpose_kernel<<<dim3(PPB / 64, (L[l].D + 63) / 64, NBATCH), 256, 0, stream>>>(
        L[l].Xin, L[l].ldx, L[l].D, XTbuf);
    if (L[l].D == 134)
      knn4_kernel<134><<<dim3(PPB / 8, NBATCH), 256, 0, stream>>>(
          L[l].Xin, L[l].ldx, XTbuf, sqbuf, idxbuf);
    else if (L[l].D == 64)
      knn4_kernel<64><<<dim3(PPB / 8, NBATCH), 256, 0, stream>>>(
          L[l].Xin, L[l].ldx, XTbuf, sqbuf, idxbuf);
    else
      knn4_kernel<128><<<dim3(PPB / 8, NBATCH), 256, 0, stream>>>(
          L[l].Xin, L[l].ldx, XTbuf, sqbuf, idxbuf);
    // A = X @ Wa.T ; Pb = X @ Wb.T
    if (L[l].M == 64) {
      gemm_kernel<64, 4><<<dim3(1, N / 128), 256, 0, stream>>>(
          L[l].Xin, L[l].ldx, L[l].W, L[l].ldw, nullptr, Abuf, 64, L[l].D);
      gemm_kernel<64, 4><<<dim3(1, N / 128), 256, 0, stream>>>(
          L[l].Xin, L[l].ldx, L[l].W + L[l].D, L[l].ldw, nullptr, Pbbuf, 64, L[l].D);
    } else {
      gemm_kernel<128, 8><<<dim3(L[l].M / 128, N / 128), 256, 0, stream>>>(
          L[l].Xin, L[l].ldx, L[l].W, L[l].ldw, nullptr, Abuf, L[l].M, L[l].D);
      gemm_kernel<128, 8><<<dim3(L[l].M / 128, N / 128), 256, 0, stream>>>(
          L[l].Xin, L[l].ldx, L[l].W + L[l].D, L[l].ldw, nullptr, Pbbuf, L[l].M, L[l].D);
    }
    edge_out_kernel<<<N, 256, 0, stream>>>(
        Abuf, Pbbuf, L[l].M, L[l].bias, idxbuf, L[l].Yout, 576);
  }

  // fc1 + max over points
  fc1max_kernel<<<dim3(1024 / 128, PPB / 128, NBATCH), 256, 0, stream>>>(
      catbuf, 576, Wfc1, 576, bfc1, partial, 576);
  gmax_kernel<<<dim3(1024 / 256, NBATCH), 256, 0, stream>>>(partial, g);

  // head MLP
  mlp_kernel<<<dim3(2, NBATCH), 256, 0, stream>>>(g,  Wfa, bfa, ga, 1024, 512, 1);
  mlp_kernel<<<dim3(1, NBATCH), 256, 0, stream>>>(ga, Wfb, bfb, gb, 512, 256, 1);
  final_kernel<<<NBATCH, 64, 0, stream>>>(gb, Wfc, bfc, out);
}

// Round 5
// 1765.669 us; speedup vs baseline: 1.4473x; 1.4473x over previous
//
#include <hip/hip_runtime.h>
#include <math.h>

#define PPB 2048
#define NBATCH 8
#define KNN 20

// ---------------------------------------------------------------------------
// Register-tiled fp32 GEMM: Y[i][m] = sum_k X[i*ldx+k]*W[m*ldw+k] (+bias[m])
// Block tile 128(i) x BN(m), thread tile 8 x TN, K-tile 8, 256 threads.
// ---------------------------------------------------------------------------
template <int BN, int TN>
__global__ __launch_bounds__(256) void gemm_kernel(
    const float* __restrict__ X, int ldx,
    const float* __restrict__ W, int ldw,
    const float* __restrict__ bias,
    float* __restrict__ Y, int ldy, int D) {
  __shared__ float Xs[8][132];
  __shared__ float Ws[8][BN + 4];
  int t = threadIdx.x;
  int tx = t & 15, ty = t >> 4;
  int i0 = blockIdx.y * 128, m0 = blockIdx.x * BN;
  float acc[8][TN];
#pragma unroll
  for (int r = 0; r < 8; ++r)
#pragma unroll
    for (int n = 0; n < TN; ++n) acc[r][n] = 0.f;

  for (int k0 = 0; k0 < D; k0 += 8) {
#pragma unroll
    for (int p = 0; p < 4; ++p) {
      int e = t + p * 256, r = e >> 3, c = e & 7, k = k0 + c;
      Xs[c][r] = (k < D) ? X[(size_t)(i0 + r) * ldx + k] : 0.f;
    }
#pragma unroll
    for (int p = 0; p < BN * 8 / 256; ++p) {
      int e = t + p * 256, r = e >> 3, c = e & 7, k = k0 + c;
      Ws[c][r] = (k < D) ? W[(size_t)(m0 + r) * ldw + k] : 0.f;
    }
    __syncthreads();
#pragma unroll
    for (int k = 0; k < 8; ++k) {
      float4 a0 = *(const float4*)&Xs[k][ty * 8];
      float4 a1 = *(const float4*)&Xs[k][ty * 8 + 4];
      float a[8] = {a0.x, a0.y, a0.z, a0.w, a1.x, a1.y, a1.z, a1.w};
      float b[TN];
#pragma unroll
      for (int n4 = 0; n4 < TN / 4; ++n4) {
        float4 bb = *(const float4*)&Ws[k][tx * TN + n4 * 4];
        b[n4 * 4 + 0] = bb.x; b[n4 * 4 + 1] = bb.y;
        b[n4 * 4 + 2] = bb.z; b[n4 * 4 + 3] = bb.w;
      }
#pragma unroll
      for (int r = 0; r < 8; ++r)
#pragma unroll
        for (int n = 0; n < TN; ++n) acc[r][n] += a[r] * b[n];
    }
    __syncthreads();
  }
#pragma unroll
  for (int r = 0; r < 8; ++r) {
    size_t row = (size_t)(i0 + ty * 8 + r) * ldy + m0 + tx * TN;
#pragma unroll
    for (int n4 = 0; n4 < TN / 4; ++n4) {
      float4 o;
      o.x = acc[r][n4 * 4 + 0]; o.y = acc[r][n4 * 4 + 1];
      o.z = acc[r][n4 * 4 + 2]; o.w = acc[r][n4 * 4 + 3];
      if (bias) {
        const float* bp = bias + m0 + tx * TN + n4 * 4;
        o.x += bp[0]; o.y += bp[1]; o.z += bp[2]; o.w += bp[3];
      }
      *(float4*)&Y[row + n4 * 4] = o;
    }
  }
}

// ---------------------------------------------------------------------------
// fc1 GEMM (576 -> 1024) fused with max over the 128-point block tile.
// ---------------------------------------------------------------------------
__global__ __launch_bounds__(256) void fc1max_kernel(
    const float* __restrict__ X, int ldx,
    const float* __restrict__ W, int ldw,
    const float* __restrict__ bias,
    float* __restrict__ partial, int D) {
  __shared__ float Xs[8][132];
  __shared__ float Ws[8][132];
  __shared__ float red[16][128];
  int t = threadIdx.x;
  int tx = t & 15, ty = t >> 4;
  int b = blockIdx.z, pt = blockIdx.y;
  int i0 = b * PPB + pt * 128;
  int m0 = blockIdx.x * 128;
  float acc[8][8];
#pragma unroll
  for (int r = 0; r < 8; ++r)
#pragma unroll
    for (int n = 0; n < 8; ++n) acc[r][n] = 0.f;

  for (int k0 = 0; k0 < D; k0 += 8) {
#pragma unroll
    for (int p = 0; p < 4; ++p) {
      int e = t + p * 256, r = e >> 3, c = e & 7, k = k0 + c;
      Xs[c][r] = (k < D) ? X[(size_t)(i0 + r) * ldx + k] : 0.f;
      Ws[c][r] = (k < D) ? W[(size_t)(m0 + r) * ldw + k] : 0.f;
    }
    __syncthreads();
#pragma unroll
    for (int k = 0; k < 8; ++k) {
      float4 a0 = *(const float4*)&Xs[k][ty * 8];
      float4 a1 = *(const float4*)&Xs[k][ty * 8 + 4];
      float a[8] = {a0.x, a0.y, a0.z, a0.w, a1.x, a1.y, a1.z, a1.w};
      float4 b0 = *(const float4*)&Ws[k][tx * 8];
      float4 b1 = *(const float4*)&Ws[k][tx * 8 + 4];
      float bb[8] = {b0.x, b0.y, b0.z, b0.w, b1.x, b1.y, b1.z, b1.w};
#pragma unroll
      for (int r = 0; r < 8; ++r)
#pragma unroll
        for (int n = 0; n < 8; ++n) acc[r][n] += a[r] * bb[n];
    }
    __syncthreads();
  }
  float tmax[8];
#pragma unroll
  for (int n = 0; n < 8; ++n) {
    float m = acc[0][n];
#pragma unroll
    for (int r = 1; r < 8; ++r) m = fmaxf(m, acc[r][n]);
    tmax[n] = m + bias[m0 + tx * 8 + n];
  }
#pragma unroll
  for (int n = 0; n < 8; ++n) red[ty][tx * 8 + n] = tmax[n];
  __syncthreads();
  for (int off = 8; off > 0; off >>= 1) {
    if (ty < off) {
#pragma unroll
      for (int n = 0; n < 8; ++n)
        red[ty][tx * 8 + n] = fmaxf(red[ty][tx * 8 + n], red[ty + off][tx * 8 + n]);
    }
    __syncthreads();
  }
  if (ty == 0) {
#pragma unroll
    for (int n = 0; n < 8; ++n)
      partial[((size_t)b * 16 + pt) * 1024 + m0 + tx * 8 + n] = red[0][tx * 8 + n];
  }
}

__global__ __launch_bounds__(256) void gmax_kernel(
    const float* __restrict__ partial, float* __restrict__ g) {
  int b = blockIdx.y;
  int m = blockIdx.x * 256 + threadIdx.x;
  float mx = -INFINITY;
  for (int pt = 0; pt < 16; ++pt)
    mx = fmaxf(mx, partial[((size_t)b * 16 + pt) * 1024 + m]);
  g[b * 1024 + m] = mx;
}

// ---------------------------------------------------------------------------
__global__ __launch_bounds__(192) void h0_kernel(
    const float* __restrict__ pos, const float* __restrict__ xin,
    const float* __restrict__ catbuf, float* __restrict__ h0) {
  int i = blockIdx.x;
  int d = threadIdx.x;
  if (d < 3)        h0[(size_t)i * 134 + d] = pos[i * 3 + d];
  else if (d < 6)   h0[(size_t)i * 134 + d] = xin[i * 3 + d - 3];
  else if (d < 134) h0[(size_t)i * 134 + d] = catbuf[(size_t)i * 576 + 448 + (d - 6)];
}

__global__ __launch_bounds__(64) void sq_kernel(
    const float* __restrict__ X, int ldx, int D, float* __restrict__ sq) {
  int i = blockIdx.x;
  int t = threadIdx.x;
  float s = 0.f;
  for (int k = t; k < D; k += 64) {
    float v = X[(size_t)i * ldx + k];
    s += v * v;
  }
  for (int off = 32; off > 0; off >>= 1) s += __shfl_down(s, off);
  if (t == 0) sq[i] = s;
}

// ---------------------------------------------------------------------------
// Transpose per batch: XT[b][k][j] = X[b*PPB+j][k]
// ---------------------------------------------------------------------------
__global__ __launch_bounds__(256) void transpose_kernel(
    const float* __restrict__ X, int ldx, int D, float* __restrict__ XT) {
  __shared__ float Ts[64][65];
  int b = blockIdx.z;
  int j0 = blockIdx.x * 64;
  int k0 = blockIdx.y * 64;
  int t = threadIdx.x;
#pragma unroll
  for (int p = 0; p < 16; ++p) {
    int e = t + p * 256, r = e >> 6, c = e & 63;
    Ts[r][c] = (k0 + c < D) ? X[(size_t)(b * PPB + j0 + r) * ldx + k0 + c] : 0.f;
  }
  __syncthreads();
#pragma unroll
  for (int p = 0; p < 16; ++p) {
    int e = t + p * 256, r = e >> 6, c = e & 63;
    if (k0 + r < D)
      XT[((size_t)b * D + k0 + r) * PPB + j0 + c] = Ts[c][r];
  }
}

// ---------------------------------------------------------------------------
// knn5: knn3's MAC loop (scalar loads, no spill) + TWO-pass selection through
// a 32 KB LDS buffer -> ~37 KB total LDS, 4 blocks/CU instead of 2.
// Thread t owns candidates j = t + 256*s, s=0..7.  acc[8][8] = 64 VGPRs.
// Pass p stages rows 4p..4p+3 into dist4; wave w selects row 4p+w.
// Selection indexing (j = lane + 64*m) and tie-breaking identical to knn3.
// Rank on sq[j]-2*dot (row-constant sq[i] dropped; ranking identical).
// grid: (PPB/8, NBATCH)
// ---------------------------------------------------------------------------
template <int D>
__global__ __launch_bounds__(256) void knn5_kernel(
    const float* __restrict__ X, int ldx,
    const float* __restrict__ XT,
    const float* __restrict__ sq,
    int* __restrict__ idx) {
  __shared__ float Qs[D][8];
  __shared__ float dist4[4][PPB];
  int b = blockIdx.y;
  int q0 = blockIdx.x * 8;
  int t = threadIdx.x;
  int lane = t & 63, w = t >> 6;

  for (int e = t; e < 8 * D; e += 256) {
    int q = e / D, k = e - q * D;
    Qs[k][q] = X[(size_t)(b * PPB + q0 + q) * ldx + k];
  }
  __syncthreads();

  const float* XTb = XT + (size_t)b * D * PPB;
  float acc[8][8];
#pragma unroll
  for (int q = 0; q < 8; ++q)
#pragma unroll
    for (int s = 0; s < 8; ++s) acc[q][s] = 0.f;

#pragma unroll 2
  for (int k = 0; k < D; ++k) {
    float cv[8];
    const float* cp = XTb + (size_t)k * PPB + t;
#pragma unroll
    for (int s = 0; s < 8; ++s) cv[s] = cp[256 * s];
    float4 q0v = *(const float4*)&Qs[k][0];
    float4 q1v = *(const float4*)&Qs[k][4];
    float qv[8] = {q0v.x, q0v.y, q0v.z, q0v.w, q1v.x, q1v.y, q1v.z, q1v.w};
#pragma unroll
    for (int q = 0; q < 8; ++q)
#pragma unroll
      for (int s = 0; s < 8; ++s) acc[q][s] += qv[q] * cv[s];
  }

  float sqj[8];
#pragma unroll
  for (int s = 0; s < 8; ++s) sqj[s] = sq[b * PPB + t + 256 * s];

  // two selection passes of 4 query rows each
#pragma unroll
  for (int p = 0; p < 2; ++p) {
    __syncthreads();  // pass 0: Qs reads done; pass 1: selection reads done
#pragma unroll
    for (int qq = 0; qq < 4; ++qq) {
      int q = p * 4 + qq;
#pragma unroll
      for (int s = 0; s < 8; ++s)
        dist4[qq][t + 256 * s] = sqj[s] - 2.f * acc[q][s];
    }
    __syncthreads();
    // wave w selects top-K for query p*4+w
    {
      int q = p * 4 + w;
      float v[32];
#pragma unroll
      for (int m = 0; m < 32; ++m) v[m] = dist4[w][lane + 64 * m];
#pragma unroll
      for (int s = 0; s < KNN; ++s) {
        float bv = 1e38f;
        int bm = 0;
#pragma unroll
        for (int m = 0; m < 32; ++m)
          if (v[m] < bv) { bv = v[m]; bm = m; }
        int bj = lane + 64 * bm;
#pragma unroll
        for (int o = 1; o < 64; o <<= 1) {
          float ov = __shfl_xor(bv, o);
          int oj = __shfl_xor(bj, o);
          if (ov < bv || (ov == bv && oj < bj)) { bv = ov; bj = oj; }
        }
        if (lane == 0)
          idx[(size_t)(b * PPB + q0 + q) * KNN + s] = b * PPB + bj;
        bool mine = (lane == (bj & 63));
        int wm = bj >> 6;
#pragma unroll
        for (int m = 0; m < 32; ++m)
          if (mine && m == wm) v[m] = 1e38f;
      }
    }
  }
}

// ---------------------------------------------------------------------------
// EdgeConv epilogue: Y[i][m] = A[i][m] + b[m] - Pb[i][m] + max_kk Pb[nb][m]
// ---------------------------------------------------------------------------
__global__ __launch_bounds__(256) void edge_out_kernel(
    const float* __restrict__ A, const float* __restrict__ Pb, int M,
    const float* __restrict__ bias, const int* __restrict__ idx,
    float* __restrict__ Y, int ldy) {
  int i = blockIdx.x;
  int t = threadIdx.x;
  __shared__ int nbs[KNN];
  if (t < KNN) nbs[t] = idx[(size_t)i * KNN + t];
  __syncthreads();
  for (int m = t; m < M; m += 256) {
    float mx = -INFINITY;
#pragma unroll
    for (int kk = 0; kk < KNN; ++kk)
      mx = fmaxf(mx, Pb[(size_t)nbs[kk] * M + m]);
    Y[(size_t)i * ldy + m] = A[(size_t)i * M + m] + bias[m] - Pb[(size_t)i * M + m] + mx;
  }
}

// ---------------------------------------------------------------------------
__global__ __launch_bounds__(256) void mlp_kernel(
    const float* __restrict__ X, const float* __restrict__ W,
    const float* __restrict__ bias, float* __restrict__ Y,
    int D, int M, int do_relu) {
  int b = blockIdx.y;
  int m = blockIdx.x * 256 + threadIdx.x;
  if (m >= M) return;
  const float* xr = X + (size_t)b * D;
  const float* wr = W + (size_t)m * D;
  float acc = 0.f;
  for (int k = 0; k < D; ++k) acc += xr[k] * wr[k];
  acc += bias[m];
  if (do_relu) acc = fmaxf(acc, 0.f);
  Y[(size_t)b * M + m] = acc;
}

__global__ __launch_bounds__(64) void final_kernel(
    const float* __restrict__ X, const float* __restrict__ W,
    const float* __restrict__ bias, float* __restrict__ out) {
  int b = blockIdx.x;
  int t = threadIdx.x;
  __shared__ float lg[23];
  if (t < 23) {
    const float* xr = X + (size_t)b * 256;
    const float* wr = W + (size_t)t * 256;
    float acc = bias[t];
    for (int k = 0; k < 256; ++k) acc += xr[k] * wr[k];
    lg[t] = acc;
  }
  __syncthreads();
  if (t == 0) {
    float mx = lg[0];
    for (int c = 1; c < 23; ++c) mx = fmaxf(mx, lg[c]);
    float s = 0.f;
    for (int c = 0; c < 23; ++c) s += expf(lg[c] - mx);
    float lse = mx + logf(s);
    for (int c = 0; c < 23; ++c) out[b * 23 + c] = lg[c] - lse;
  }
}

// ---------------------------------------------------------------------------

extern "C" void kernel_launch(void* const* d_in, const int* in_sizes, int n_in,
                              void* d_out, int out_size, void* d_ws, size_t ws_size,
                              hipStream_t stream) {
  const float* pos      = (const float*)d_in[0];
  const float* xin      = (const float*)d_in[1];
  const float* features = (const float*)d_in[2];
  const float* Wf   = (const float*)d_in[4];
  const float* bf   = (const float*)d_in[5];
  const float* W1   = (const float*)d_in[6];
  const float* b1   = (const float*)d_in[7];
  const float* W2   = (const float*)d_in[8];
  const float* b2   = (const float*)d_in[9];
  const float* W3   = (const float*)d_in[10];
  const float* b3   = (const float*)d_in[11];
  const float* Wfc1 = (const float*)d_in[12];
  const float* bfc1 = (const float*)d_in[13];
  const float* Wfa  = (const float*)d_in[14];
  const float* bfa  = (const float*)d_in[15];
  const float* Wfb  = (const float*)d_in[16];
  const float* bfb  = (const float*)d_in[17];
  const float* Wfc  = (const float*)d_in[18];
  const float* bfc  = (const float*)d_in[19];
  float* out = (float*)d_out;

  const int N = in_sizes[0] / 3;  // 16384

  char* base = (char*)d_ws;
  size_t off = 0;
  auto alloc = [&](size_t bytes) {
    void* p = base + off;
    off += (bytes + 255) & ~(size_t)255;
    return p;
  };
  float* catbuf  = (float*)alloc((size_t)N * 576 * 4);  // [x1|x2|x3|feats]
  float* h0      = (float*)alloc((size_t)N * 134 * 4);
  float* Abuf    = (float*)alloc((size_t)N * 256 * 4);
  float* Pbbuf   = (float*)alloc((size_t)N * 256 * 4);
  float* XTbuf   = (float*)alloc((size_t)N * 134 * 4);
  float* sqbuf   = (float*)alloc((size_t)N * 4);
  int*   idxbuf  = (int*)  alloc((size_t)N * KNN * 4);
  float* partial = (float*)alloc((size_t)NBATCH * 16 * 1024 * 4);
  float* g       = (float*)alloc((size_t)NBATCH * 1024 * 4);
  float* ga      = (float*)alloc((size_t)NBATCH * 512 * 4);
  float* gb      = (float*)alloc((size_t)NBATCH * 256 * 4);
  (void)ws_size;

  // 1. feats = features @ Wf.T + bf  -> catbuf[:,448:576]
  gemm_kernel<128, 8><<<dim3(1, N / 128), 256, 0, stream>>>(
      features, 1344, Wf, 1344, bf, catbuf + 448, 576, 1344);

  // 2. h0 = [pos | x | feats]
  h0_kernel<<<N, 192, 0, stream>>>(pos, xin, catbuf, h0);

  struct Layer {
    const float* Xin; int ldx; int D;
    const float* W; int ldw;
    const float* bias; int M;
    float* Yout;
  };
  Layer L[3] = {
      {h0,          134, 134, W1, 268, b1,  64, catbuf + 0},
      {catbuf + 0,  576,  64, W2, 128, b2, 128, catbuf + 64},
      {catbuf + 64, 576, 128, W3, 256, b3, 256, catbuf + 192},
  };

  for (int l = 0; l < 3; ++l) {
    sq_kernel<<<N, 64, 0, stream>>>(L[l].Xin, L[l].ldx, L[l].D, sqbuf);
    transpose_kernel<<<dim3(PPB / 64, (L[l].D + 63) / 64, NBATCH), 256, 0, stream>>>(
        L[l].Xin, L[l].ldx, L[l].D, XTbuf);
    if (L[l].D == 134)
      knn5_kernel<134><<<dim3(PPB / 8, NBATCH), 256, 0, stream>>>(
          L[l].Xin, L[l].ldx, XTbuf, sqbuf, idxbuf);
    else if (L[l].D == 64)
      knn5_kernel<64><<<dim3(PPB / 8, NBATCH), 256, 0, stream>>>(
          L[l].Xin, L[l].ldx, XTbuf, sqbuf, idxbuf);
    else
      knn5_kernel<128><<<dim3(PPB / 8, NBATCH), 256, 0, stream>>>(
          L[l].Xin, L[l].ldx, XTbuf, sqbuf, idxbuf);
    // A = X @ Wa.T ; Pb = X @ Wb.T
    if (L[l].M == 64) {
      gemm_kernel<64, 4><<<dim3(1, N / 128), 256, 0, stream>>>(
          L[l].Xin, L[l].ldx, L[l].W, L[l].ldw, nullptr, Abuf, 64, L[l].D);
      gemm_kernel<64, 4><<<dim3(1, N / 128), 256, 0, stream>>>(
          L[l].Xin, L[l].ldx, L[l].W + L[l].D, L[l].ldw, nullptr, Pbbuf, 64, L[l].D);
    } else {
      gemm_kernel<128, 8><<<dim3(L[l].M / 128, N / 128), 256, 0, stream>>>(
          L[l].Xin, L[l].ldx, L[l].W, L[l].ldw, nullptr, Abuf, L[l].M, L[l].D);
      gemm_kernel<128, 8><<<dim3(L[l].M / 128, N / 128), 256, 0, stream>>>(
          L[l].Xin, L[l].ldx, L[l].W + L[l].D, L[l].ldw, nullptr, Pbbuf, L[l].M, L[l].D);
    }
    edge_out_kernel<<<N, 256, 0, stream>>>(
        Abuf, Pbbuf, L[l].M, L[l].bias, idxbuf, L[l].Yout, 576);
  }

  // fc1 + max over points
  fc1max_kernel<<<dim3(1024 / 128, PPB / 128, NBATCH), 256, 0, stream>>>(
      catbuf, 576, Wfc1, 576, bfc1, partial, 576);
  gmax_kernel<<<dim3(1024 / 256, NBATCH), 256, 0, stream>>>(partial, g);

  // head MLP
  mlp_kernel<<<dim3(2, NBATCH), 256, 0, stream>>>(g,  Wfa, bfa, ga, 1024, 512, 1);
  mlp_kernel<<<dim3(1, NBATCH), 256, 0, stream>>>(ga, Wfb, bfb, gb, 512, 256, 1);
  final_kernel<<<NBATCH, 64, 0, stream>>>(gb, Wfc, bfc, out);
}

// Round 6
// 1284.204 us; speedup vs baseline: 1.9899x; 1.3749x over previous
//
#include <hip/hip_runtime.h>
#include <math.h>

#define PPB 2048
#define NBATCH 8
#define KNN 20

typedef __attribute__((ext_vector_type(8))) short short8;
typedef __attribute__((ext_vector_type(8))) __bf16 bf16x8;
typedef __attribute__((ext_vector_type(4))) float f32x4;

// ---------------------------------------------------------------------------
// feats GEMM with split-K=4: fpart[kc][i][m] = X[i][kc*336..]*Wf[m][kc*336..]
// block tile 128x128, thread 8x8, K-tile 8.  grid (1, N/128, 4).
// ---------------------------------------------------------------------------
__global__ __launch_bounds__(256) void gemm_feats_kernel(
    const float* __restrict__ X, const float* __restrict__ W,
    float* __restrict__ fpart, int N) {
  const int KC = 336;
  int kc = blockIdx.z;
  const float* Xp = X + kc * KC;
  const float* Wp = W + kc * KC;
  float* Y = fpart + (size_t)kc * N * 128;
  __shared__ float Xs[8][132];
  __shared__ float Ws[8][132];
  int t = threadIdx.x;
  int tx = t & 15, ty = t >> 4;
  int i0 = blockIdx.y * 128;
  float acc[8][8];
#pragma unroll
  for (int r = 0; r < 8; ++r)
#pragma unroll
    for (int n = 0; n < 8; ++n) acc[r][n] = 0.f;

  for (int k0 = 0; k0 < KC; k0 += 8) {
#pragma unroll
    for (int p = 0; p < 4; ++p) {
      int e = t + p * 256, r = e >> 3, c = e & 7, k = k0 + c;
      Xs[c][r] = Xp[(size_t)(i0 + r) * 1344 + k];
      Ws[c][r] = Wp[(size_t)r * 1344 + k];
    }
    __syncthreads();
#pragma unroll
    for (int k = 0; k < 8; ++k) {
      float4 a0 = *(const float4*)&Xs[k][ty * 8];
      float4 a1 = *(const float4*)&Xs[k][ty * 8 + 4];
      float a[8] = {a0.x, a0.y, a0.z, a0.w, a1.x, a1.y, a1.z, a1.w};
      float4 b0 = *(const float4*)&Ws[k][tx * 8];
      float4 b1 = *(const float4*)&Ws[k][tx * 8 + 4];
      float bb[8] = {b0.x, b0.y, b0.z, b0.w, b1.x, b1.y, b1.z, b1.w};
#pragma unroll
      for (int r = 0; r < 8; ++r)
#pragma unroll
        for (int n = 0; n < 8; ++n) acc[r][n] += a[r] * bb[n];
    }
    __syncthreads();
  }
#pragma unroll
  for (int r = 0; r < 8; ++r) {
    size_t row = (size_t)(i0 + ty * 8 + r) * 128 + tx * 8;
#pragma unroll
    for (int n4 = 0; n4 < 2; ++n4) {
      float4 o;
      o.x = acc[r][n4 * 4 + 0]; o.y = acc[r][n4 * 4 + 1];
      o.z = acc[r][n4 * 4 + 2]; o.w = acc[r][n4 * 4 + 3];
      *(float4*)&Y[row + n4 * 4] = o;
    }
  }
}

// reduce 4 K-partials + bias -> catbuf[:,448:576]
__global__ __launch_bounds__(256) void reduce_feats_kernel(
    const float* __restrict__ fpart, const float* __restrict__ bias,
    float* __restrict__ catbuf, int N) {
  int e = blockIdx.x * 256 + threadIdx.x;
  size_t NP = (size_t)N * 128;
  int i = e >> 7, m = e & 127;
  float s = bias[m] + fpart[e] + fpart[NP + e] + fpart[2 * NP + e] + fpart[3 * NP + e];
  catbuf[(size_t)i * 576 + 448 + m] = s;
}

// ---------------------------------------------------------------------------
// Fused EdgeConv A/Pb GEMM: one launch covers both Wa and Wb halves.
// tile 64(i) x 64(m), thread 4x4, K-tile 16.  grid ((2M)/64, N/64).
// ---------------------------------------------------------------------------
__global__ __launch_bounds__(256) void edge_gemm_kernel(
    const float* __restrict__ X, int ldx, int D,
    const float* __restrict__ W, int ldw, int M,
    float* __restrict__ A, float* __restrict__ Pb) {
  __shared__ float Xs[16][68];
  __shared__ float Ws[16][68];
  int t = threadIdx.x, tx = t & 15, ty = t >> 4;
  int nHalf = M >> 6;
  int mt = blockIdx.x;
  int is_b = (mt >= nHalf) ? 1 : 0;
  int m0 = (is_b ? mt - nHalf : mt) << 6;
  int koff = is_b ? D : 0;
  float* __restrict__ out = is_b ? Pb : A;
  int i0 = blockIdx.y * 64;
  float acc[4][4];
#pragma unroll
  for (int r = 0; r < 4; ++r)
#pragma unroll
    for (int n = 0; n < 4; ++n) acc[r][n] = 0.f;

  for (int k0 = 0; k0 < D; k0 += 16) {
#pragma unroll
    for (int p = 0; p < 4; ++p) {
      int e = t + p * 256, r = e >> 4, c = e & 15, k = k0 + c;
      Xs[c][r] = (k < D) ? X[(size_t)(i0 + r) * ldx + k] : 0.f;
      Ws[c][r] = (k < D) ? W[(size_t)(m0 + r) * ldw + koff + k] : 0.f;
    }
    __syncthreads();
#pragma unroll
    for (int kk = 0; kk < 16; ++kk) {
      float4 a4 = *(const float4*)&Xs[kk][ty * 4];
      float4 b4 = *(const float4*)&Ws[kk][tx * 4];
      float a[4] = {a4.x, a4.y, a4.z, a4.w};
      float bb[4] = {b4.x, b4.y, b4.z, b4.w};
#pragma unroll
      for (int r = 0; r < 4; ++r)
#pragma unroll
        for (int n = 0; n < 4; ++n) acc[r][n] += a[r] * bb[n];
    }
    __syncthreads();
  }
#pragma unroll
  for (int r = 0; r < 4; ++r) {
    float4 o;
    o.x = acc[r][0]; o.y = acc[r][1]; o.z = acc[r][2]; o.w = acc[r][3];
    *(float4*)&out[(size_t)(i0 + ty * 4 + r) * M + m0 + tx * 4] = o;
  }
}

// ---------------------------------------------------------------------------
// fp32 -> bf16 (RNE) cast, 4 elements/thread
// ---------------------------------------------------------------------------
__global__ __launch_bounds__(256) void cast_bf16_kernel(
    const float* __restrict__ src, unsigned short* __restrict__ dst, int n) {
  int e4 = (blockIdx.x * 256 + threadIdx.x) * 4;
  if (e4 >= n) return;
  float4 v = *(const float4*)&src[e4];
  ushort4 o;
  unsigned int u;
  u = __float_as_uint(v.x); o.x = (unsigned short)((u + 0x7fff + ((u >> 16) & 1)) >> 16);
  u = __float_as_uint(v.y); o.y = (unsigned short)((u + 0x7fff + ((u >> 16) & 1)) >> 16);
  u = __float_as_uint(v.z); o.z = (unsigned short)((u + 0x7fff + ((u >> 16) & 1)) >> 16);
  u = __float_as_uint(v.w); o.w = (unsigned short)((u + 0x7fff + ((u >> 16) & 1)) >> 16);
  *(ushort4*)&dst[e4] = o;
}

// ---------------------------------------------------------------------------
// fc1 (576 -> 1024) via bf16 MFMA, fused max over 64-point tile.
// block 256 = 4 waves; tile 64 pts x 64 m; wave w owns rows 16w..16w+15.
// grid (1024/64, PPB/64, NBATCH).
// ---------------------------------------------------------------------------
__global__ __launch_bounds__(256) void fc1max_mfma_kernel(
    const unsigned short* __restrict__ Xb, const unsigned short* __restrict__ Wb,
    const float* __restrict__ bias, float* __restrict__ partial) {
  __shared__ unsigned short Xs[64][40];
  __shared__ unsigned short Ws[64][40];
  __shared__ float red[4][64];
  int t = threadIdx.x;
  int l = t & 63, w = t >> 6;
  int b = blockIdx.z, pt = blockIdx.y;
  int i0 = b * PPB + pt * 64;
  int m0 = blockIdx.x * 64;
  int r_st = t >> 2;
  int c_st = (t & 3) * 8;

  f32x4 acc[4];
#pragma unroll
  for (int g = 0; g < 4; ++g) acc[g] = (f32x4){0.f, 0.f, 0.f, 0.f};

  for (int k0 = 0; k0 < 576; k0 += 32) {
    short8 xv = *(const short8*)&Xb[(size_t)(i0 + r_st) * 576 + k0 + c_st];
    short8 wv = *(const short8*)&Wb[(size_t)(m0 + r_st) * 576 + k0 + c_st];
    __syncthreads();
    *(short8*)&Xs[r_st][c_st] = xv;
    *(short8*)&Ws[r_st][c_st] = wv;
    __syncthreads();
    short8 ar = *(const short8*)&Xs[16 * w + (l & 15)][(l >> 4) * 8];
    bf16x8 av = __builtin_bit_cast(bf16x8, ar);
#pragma unroll
    for (int g = 0; g < 4; ++g) {
      short8 br = *(const short8*)&Ws[g * 16 + (l & 15)][(l >> 4) * 8];
      bf16x8 bv = __builtin_bit_cast(bf16x8, br);
      acc[g] = __builtin_amdgcn_mfma_f32_16x16x32_bf16(av, bv, acc[g], 0, 0, 0);
    }
  }
  // max over this wave's 16 rows, per column
  float pm[4];
#pragma unroll
  for (int g = 0; g < 4; ++g) {
    float m = fmaxf(fmaxf(acc[g][0], acc[g][1]), fmaxf(acc[g][2], acc[g][3]));
    m = fmaxf(m, __shfl_xor(m, 16));
    m = fmaxf(m, __shfl_xor(m, 32));
    pm[g] = m;
  }
  if (l < 16) {
#pragma unroll
    for (int g = 0; g < 4; ++g) red[w][g * 16 + l] = pm[g];
  }
  __syncthreads();
  if (t < 64) {
    float mx = fmaxf(fmaxf(red[0][t], red[1][t]), fmaxf(red[2][t], red[3][t]));
    partial[((size_t)b * (PPB / 64) + pt) * 1024 + m0 + t] = mx + bias[m0 + t];
  }
}

__global__ __launch_bounds__(256) void gmax_kernel(
    const float* __restrict__ partial, float* __restrict__ g) {
  int b = blockIdx.y;
  int m = blockIdx.x * 256 + threadIdx.x;
  float mx = -INFINITY;
  for (int pt = 0; pt < PPB / 64; ++pt)
    mx = fmaxf(mx, partial[((size_t)b * (PPB / 64) + pt) * 1024 + m]);
  g[b * 1024 + m] = mx;
}

// ---------------------------------------------------------------------------
__global__ __launch_bounds__(192) void h0_kernel(
    const float* __restrict__ pos, const float* __restrict__ xin,
    const float* __restrict__ catbuf, float* __restrict__ h0) {
  int i = blockIdx.x;
  int d = threadIdx.x;
  if (d < 3)        h0[(size_t)i * 134 + d] = pos[i * 3 + d];
  else if (d < 6)   h0[(size_t)i * 134 + d] = xin[i * 3 + d - 3];
  else if (d < 134) h0[(size_t)i * 134 + d] = catbuf[(size_t)i * 576 + 448 + (d - 6)];
}

__global__ __launch_bounds__(64) void sq_kernel(
    const float* __restrict__ X, int ldx, int D, float* __restrict__ sq) {
  int i = blockIdx.x;
  int t = threadIdx.x;
  float s = 0.f;
  for (int k = t; k < D; k += 64) {
    float v = X[(size_t)i * ldx + k];
    s += v * v;
  }
  for (int off = 32; off > 0; off >>= 1) s += __shfl_down(s, off);
  if (t == 0) sq[i] = s;
}

// ---------------------------------------------------------------------------
// Transpose per batch: XT[b][k][j] = X[b*PPB+j][k]
// ---------------------------------------------------------------------------
__global__ __launch_bounds__(256) void transpose_kernel(
    const float* __restrict__ X, int ldx, int D, float* __restrict__ XT) {
  __shared__ float Ts[64][65];
  int b = blockIdx.z;
  int j0 = blockIdx.x * 64;
  int k0 = blockIdx.y * 64;
  int t = threadIdx.x;
#pragma unroll
  for (int p = 0; p < 16; ++p) {
    int e = t + p * 256, r = e >> 6, c = e & 63;
    Ts[r][c] = (k0 + c < D) ? X[(size_t)(b * PPB + j0 + r) * ldx + k0 + c] : 0.f;
  }
  __syncthreads();
#pragma unroll
  for (int p = 0; p < 16; ++p) {
    int e = t + p * 256, r = e >> 6, c = e & 63;
    if (k0 + r < D)
      XT[((size_t)b * D + k0 + r) * PPB + j0 + c] = Ts[c][r];
  }
}

// ---------------------------------------------------------------------------
// knn5 (unchanged from round 5): scalar MAC loop, two-pass LDS selection.
// ---------------------------------------------------------------------------
template <int D>
__global__ __launch_bounds__(256) void knn5_kernel(
    const float* __restrict__ X, int ldx,
    const float* __restrict__ XT,
    const float* __restrict__ sq,
    int* __restrict__ idx) {
  __shared__ float Qs[D][8];
  __shared__ float dist4[4][PPB];
  int b = blockIdx.y;
  int q0 = blockIdx.x * 8;
  int t = threadIdx.x;
  int lane = t & 63, w = t >> 6;

  for (int e = t; e < 8 * D; e += 256) {
    int q = e / D, k = e - q * D;
    Qs[k][q] = X[(size_t)(b * PPB + q0 + q) * ldx + k];
  }
  __syncthreads();

  const float* XTb = XT + (size_t)b * D * PPB;
  float acc[8][8];
#pragma unroll
  for (int q = 0; q < 8; ++q)
#pragma unroll
    for (int s = 0; s < 8; ++s) acc[q][s] = 0.f;

#pragma unroll 2
  for (int k = 0; k < D; ++k) {
    float cv[8];
    const float* cp = XTb + (size_t)k * PPB + t;
#pragma unroll
    for (int s = 0; s < 8; ++s) cv[s] = cp[256 * s];
    float4 q0v = *(const float4*)&Qs[k][0];
    float4 q1v = *(const float4*)&Qs[k][4];
    float qv[8] = {q0v.x, q0v.y, q0v.z, q0v.w, q1v.x, q1v.y, q1v.z, q1v.w};
#pragma unroll
    for (int q = 0; q < 8; ++q)
#pragma unroll
      for (int s = 0; s < 8; ++s) acc[q][s] += qv[q] * cv[s];
  }

  float sqj[8];
#pragma unroll
  for (int s = 0; s < 8; ++s) sqj[s] = sq[b * PPB + t + 256 * s];

#pragma unroll
  for (int p = 0; p < 2; ++p) {
    __syncthreads();
#pragma unroll
    for (int qq = 0; qq < 4; ++qq) {
      int q = p * 4 + qq;
#pragma unroll
      for (int s = 0; s < 8; ++s)
        dist4[qq][t + 256 * s] = sqj[s] - 2.f * acc[q][s];
    }
    __syncthreads();
    {
      int q = p * 4 + w;
      float v[32];
#pragma unroll
      for (int m = 0; m < 32; ++m) v[m] = dist4[w][lane + 64 * m];
#pragma unroll
      for (int s = 0; s < KNN; ++s) {
        float bv = 1e38f;
        int bm = 0;
#pragma unroll
        for (int m = 0; m < 32; ++m)
          if (v[m] < bv) { bv = v[m]; bm = m; }
        int bj = lane + 64 * bm;
#pragma unroll
        for (int o = 1; o < 64; o <<= 1) {
          float ov = __shfl_xor(bv, o);
          int oj = __shfl_xor(bj, o);
          if (ov < bv || (ov == bv && oj < bj)) { bv = ov; bj = oj; }
        }
        if (lane == 0)
          idx[(size_t)(b * PPB + q0 + q) * KNN + s] = b * PPB + bj;
        bool mine = (lane == (bj & 63));
        int wm = bj >> 6;
#pragma unroll
        for (int m = 0; m < 32; ++m)
          if (mine && m == wm) v[m] = 1e38f;
      }
    }
  }
}

// ---------------------------------------------------------------------------
// EdgeConv epilogue: Y[i][m] = A[i][m] + b[m] - Pb[i][m] + max_kk Pb[nb][m]
// ---------------------------------------------------------------------------
__global__ __launch_bounds__(256) void edge_out_kernel(
    const float* __restrict__ A, const float* __restrict__ Pb, int M,
    const float* __restrict__ bias, const int* __restrict__ idx,
    float* __restrict__ Y, int ldy) {
  int i = blockIdx.x;
  int t = threadIdx.x;
  __shared__ int nbs[KNN];
  if (t < KNN) nbs[t] = idx[(size_t)i * KNN + t];
  __syncthreads();
  for (int m = t; m < M; m += 256) {
    float mx = -INFINITY;
#pragma unroll
    for (int kk = 0; kk < KNN; ++kk)
      mx = fmaxf(mx, Pb[(size_t)nbs[kk] * M + m]);
    Y[(size_t)i * ldy + m] = A[(size_t)i * M + m] + bias[m] - Pb[(size_t)i * M + m] + mx;
  }
}

// ---------------------------------------------------------------------------
__global__ __launch_bounds__(256) void mlp_kernel(
    const float* __restrict__ X, const float* __restrict__ W,
    const float* __restrict__ bias, float* __restrict__ Y,
    int D, int M, int do_relu) {
  int b = blockIdx.y;
  int m = blockIdx.x * 256 + threadIdx.x;
  if (m >= M) return;
  const float* xr = X + (size_t)b * D;
  const float* wr = W + (size_t)m * D;
  float acc = 0.f;
  for (int k = 0; k < D; ++k) acc += xr[k] * wr[k];
  acc += bias[m];
  if (do_relu) acc = fmaxf(acc, 0.f);
  Y[(size_t)b * M + m] = acc;
}

__global__ __launch_bounds__(64) void final_kernel(
    const float* __restrict__ X, const float* __restrict__ W,
    const float* __restrict__ bias, float* __restrict__ out) {
  int b = blockIdx.x;
  int t = threadIdx.x;
  __shared__ float lg[23];
  if (t < 23) {
    const float* xr = X + (size_t)b * 256;
    const float* wr = W + (size_t)t * 256;
    float acc = bias[t];
    for (int k = 0; k < 256; ++k) acc += xr[k] * wr[k];
    lg[t] = acc;
  }
  __syncthreads();
  if (t == 0) {
    float mx = lg[0];
    for (int c = 1; c < 23; ++c) mx = fmaxf(mx, lg[c]);
    float s = 0.f;
    for (int c = 0; c < 23; ++c) s += expf(lg[c] - mx);
    float lse = mx + logf(s);
    for (int c = 0; c < 23; ++c) out[b * 23 + c] = lg[c] - lse;
  }
}

// ---------------------------------------------------------------------------

extern "C" void kernel_launch(void* const* d_in, const int* in_sizes, int n_in,
                              void* d_out, int out_size, void* d_ws, size_t ws_size,
                              hipStream_t stream) {
  const float* pos      = (const float*)d_in[0];
  const float* xin      = (const float*)d_in[1];
  const float* features = (const float*)d_in[2];
  const float* Wf   = (const float*)d_in[4];
  const float* bf   = (const float*)d_in[5];
  const float* W1   = (const float*)d_in[6];
  const float* b1   = (const float*)d_in[7];
  const float* W2   = (const float*)d_in[8];
  const float* b2   = (const float*)d_in[9];
  const float* W3   = (const float*)d_in[10];
  const float* b3   = (const float*)d_in[11];
  const float* Wfc1 = (const float*)d_in[12];
  const float* bfc1 = (const float*)d_in[13];
  const float* Wfa  = (const float*)d_in[14];
  const float* bfa  = (const float*)d_in[15];
  const float* Wfb  = (const float*)d_in[16];
  const float* bfb  = (const float*)d_in[17];
  const float* Wfc  = (const float*)d_in[18];
  const float* bfc  = (const float*)d_in[19];
  float* out = (float*)d_out;

  const int N = in_sizes[0] / 3;  // 16384

  char* base = (char*)d_ws;
  size_t off = 0;
  auto alloc = [&](size_t bytes) {
    void* p = base + off;
    off += (bytes + 255) & ~(size_t)255;
    return p;
  };
  float* catbuf  = (float*)alloc((size_t)N * 576 * 4);  // [x1|x2|x3|feats]
  float* h0      = (float*)alloc((size_t)N * 134 * 4);
  float* Abuf    = (float*)alloc((size_t)N * 256 * 4);
  float* Pbbuf   = (float*)alloc((size_t)N * 256 * 4);
  float* XTbuf   = (float*)alloc((size_t)N * 134 * 4);
  float* sqbuf   = (float*)alloc((size_t)N * 4);
  int*   idxbuf  = (int*)  alloc((size_t)N * KNN * 4);
  float* partial = (float*)alloc((size_t)NBATCH * (PPB / 64) * 1024 * 4);
  float* g       = (float*)alloc((size_t)NBATCH * 1024 * 4);
  float* ga      = (float*)alloc((size_t)NBATCH * 512 * 4);
  float* gb      = (float*)alloc((size_t)NBATCH * 256 * 4);
  (void)ws_size;

  // aliased scratch (lifetimes verified):
  //   fpart (feats split-K partials, 33.5 MB) = Abuf+Pbbuf, used before layers
  //   catb16 (18.9 MB) = Abuf+Pbbuf, used after last edge_out
  //   Wb16 (1.2 MB) = h0, used after layer 1
  float* fpart = Abuf;
  unsigned short* catb16 = (unsigned short*)Abuf;
  unsigned short* Wb16   = (unsigned short*)h0;

  // 1. feats = features @ Wf.T + bf  (split-K=4) -> catbuf[:,448:576]
  gemm_feats_kernel<<<dim3(1, N / 128, 4), 256, 0, stream>>>(features, Wf, fpart, N);
  reduce_feats_kernel<<<(N * 128) / 256, 256, 0, stream>>>(fpart, bf, catbuf, N);

  // 2. h0 = [pos | x | feats]
  h0_kernel<<<N, 192, 0, stream>>>(pos, xin, catbuf, h0);

  struct Layer {
    const float* Xin; int ldx; int D;
    const float* W; int ldw;
    const float* bias; int M;
    float* Yout;
  };
  Layer L[3] = {
      {h0,          134, 134, W1, 268, b1,  64, catbuf + 0},
      {catbuf + 0,  576,  64, W2, 128, b2, 128, catbuf + 64},
      {catbuf + 64, 576, 128, W3, 256, b3, 256, catbuf + 192},
  };

  for (int l = 0; l < 3; ++l) {
    sq_kernel<<<N, 64, 0, stream>>>(L[l].Xin, L[l].ldx, L[l].D, sqbuf);
    transpose_kernel<<<dim3(PPB / 64, (L[l].D + 63) / 64, NBATCH), 256, 0, stream>>>(
        L[l].Xin, L[l].ldx, L[l].D, XTbuf);
    if (L[l].D == 134)
      knn5_kernel<134><<<dim3(PPB / 8, NBATCH), 256, 0, stream>>>(
          L[l].Xin, L[l].ldx, XTbuf, sqbuf, idxbuf);
    else if (L[l].D == 64)
      knn5_kernel<64><<<dim3(PPB / 8, NBATCH), 256, 0, stream>>>(
          L[l].Xin, L[l].ldx, XTbuf, sqbuf, idxbuf);
    else
      knn5_kernel<128><<<dim3(PPB / 8, NBATCH), 256, 0, stream>>>(
          L[l].Xin, L[l].ldx, XTbuf, sqbuf, idxbuf);
    // fused A = X@Wa.T and Pb = X@Wb.T
    edge_gemm_kernel<<<dim3((2 * L[l].M) / 64, N / 64), 256, 0, stream>>>(
        L[l].Xin, L[l].ldx, L[l].D, L[l].W, L[l].ldw, L[l].M, Abuf, Pbbuf);
    edge_out_kernel<<<N, 256, 0, stream>>>(
        Abuf, Pbbuf, L[l].M, L[l].bias, idxbuf, L[l].Yout, 576);
  }

  // casts for fc1 (catbuf complete; Abuf/Pbbuf/h0 dead)
  cast_bf16_kernel<<<(N * 576) / 1024, 256, 0, stream>>>(catbuf, catb16, N * 576);
  cast_bf16_kernel<<<(1024 * 576) / 1024, 256, 0, stream>>>(Wfc1, Wb16, 1024 * 576);

  // fc1 + max over points (bf16 MFMA)
  fc1max_mfma_kernel<<<dim3(1024 / 64, PPB / 64, NBATCH), 256, 0, stream>>>(
      catb16, Wb16, bfc1, partial);
  gmax_kernel<<<dim3(1024 / 256, NBATCH), 256, 0, stream>>>(partial, g);

  // head MLP
  mlp_kernel<<<dim3(2, NBATCH), 256, 0, stream>>>(g,  Wfa, bfa, ga, 1024, 512, 1);
  mlp_kernel<<<dim3(1, NBATCH), 256, 0, stream>>>(ga, Wfb, bfb, gb, 512, 256, 1);
  final_kernel<<<NBATCH, 64, 0, stream>>>(gb, Wfc, bfc, out);
}